// Round 4
// baseline (143.605 us; speedup 1.0000x reference)
//
#include <hip/hip_runtime.h>
#include <stdint.h>

// Problem: B=2, T=2048, C=1024, H=16, HD=64. M = B*T = 4096, 3C = 3072.
// Geo bias folded into Q:  q~[d] = q[d]*SCALE + hs*(q[:8]·dir)*dir[d] (d<8)
// log2(e) additionally folded into Q~ so softmax uses exp2 directly.

typedef float f32x4 __attribute__((ext_vector_type(4)));
typedef unsigned short u16x8 __attribute__((ext_vector_type(8)));
typedef unsigned short u16x4 __attribute__((ext_vector_type(4)));
typedef unsigned int u32x2 __attribute__((ext_vector_type(2)));
typedef __bf16 bf16x8 __attribute__((ext_vector_type(8)));

static __device__ __forceinline__ unsigned short f2bf(float f) {
  unsigned u = __float_as_uint(f);
  u += 0x7FFFu + ((u >> 16) & 1u);
  return (unsigned short)(u >> 16);
}
static __device__ __forceinline__ float bf2f(unsigned short s) {
  return __uint_as_float(((unsigned)s) << 16);
}
static __device__ __forceinline__ f32x4 mfma16(u16x8 a, u16x8 b, f32x4 c) {
  return __builtin_amdgcn_mfma_f32_16x16x32_bf16(
      __builtin_bit_cast(bf16x8, a), __builtin_bit_cast(bf16x8, b), c, 0, 0, 0);
}
static __device__ __forceinline__ unsigned cvtpk(float lo, float hi) {
  unsigned d;
  asm("v_cvt_pk_bf16_f32 %0, %1, %2" : "=v"(d) : "v"(lo), "v"(hi));
  return d;
}

#define GLD16(gp, lp) __builtin_amdgcn_global_load_lds( \
    (const __attribute__((address_space(1))) unsigned int*)(gp), \
    (__attribute__((address_space(3))) unsigned int*)(lp), 16, 0, 0)

// ---------------- cast x (fp32 -> bf16) ----------------
__global__ __launch_bounds__(256) void k_cast(const float* __restrict__ in,
                                              unsigned short* __restrict__ out, int n4) {
  int i = blockIdx.x * 256 + threadIdx.x;
  if (i >= n4) return;
  f32x4 v = *(const f32x4*)(in + (size_t)i * 4);
  u16x4 o;
#pragma unroll
  for (int j = 0; j < 4; ++j) o[j] = f2bf(v[j]);
  *(u16x4*)(out + (size_t)i * 4) = o;
}

// ---------------- transpose + cast: out[c][r] = bf16(in[r][c]) ----------------
__global__ __launch_bounds__(256) void k_transpose(const float* __restrict__ in,
                                                   unsigned short* __restrict__ out,
                                                   int R, int Cc) {
  __shared__ float t[64][65];
  int tr = blockIdx.y * 64, tc = blockIdx.x * 64;
  int tx = threadIdx.x & 15, ty = threadIdx.x >> 4;
#pragma unroll
  for (int i = 0; i < 4; ++i) {
    int rr = ty + i * 16;
    f32x4 v = *(const f32x4*)(in + (size_t)(tr + rr) * Cc + tc + tx * 4);
#pragma unroll
    for (int j = 0; j < 4; ++j) t[rr][tx * 4 + j] = v[j];
  }
  __syncthreads();
#pragma unroll
  for (int i = 0; i < 4; ++i) {
    int cc = ty + i * 16;
    int rr = tx * 4;
    u16x4 o;
#pragma unroll
    for (int j = 0; j < 4; ++j) o[j] = f2bf(t[rr + j][cc]);
    *(u16x4*)(out + (size_t)(tc + cc) * R + tr + rr) = o;
  }
}

// ---------------- GEMM: C[m][n] = sum_k A[m][k] * Bt[n][k]  (K=1024, 128x128 tile, BK=32)
template <int MODE>
__global__ __launch_bounds__(256) void k_gemm(const unsigned short* __restrict__ A,
                                              const unsigned short* __restrict__ Bt,
                                              unsigned short* __restrict__ qo,
                                              unsigned short* __restrict__ ko,
                                              unsigned short* __restrict__ vTo,
                                              float* __restrict__ fo) {
  __shared__ unsigned short lA[128 * 32];
  __shared__ unsigned short lB[128 * 32];
  const int tid = threadIdx.x;
  const int lane = tid & 63, wid = tid >> 6;
  const int wr = wid >> 1, wc = wid & 1;
  const int r = lane & 15, g = lane >> 4;
  const int mbase = blockIdx.y * 128;
  const int nbase = blockIdx.x * 128;

  f32x4 acc[4][4] = {};

  for (int kt = 0; kt < 32; ++kt) {
    __syncthreads();
#pragma unroll
    for (int p = 0; p < 2; ++p) {
      int L = p * 4096 + tid * 16;  // byte offset in 8KB tile
      int row = L >> 6;             // 64B per row (32 bf16)
      int blk = (L >> 4) & 3;       // 16B block within row
      GLD16(A + (size_t)(mbase + row) * 1024 + kt * 32 + blk * 8, lA + (L >> 1));
      GLD16(Bt + (size_t)(nbase + row) * 1024 + kt * 32 + blk * 8, lB + (L >> 1));
    }
    __syncthreads();
    u16x8 af[4], bfv[4];
#pragma unroll
    for (int m = 0; m < 4; ++m)
      af[m] = *(const u16x8*)(lA + (wr * 64 + m * 16 + r) * 32 + g * 8);
#pragma unroll
    for (int n = 0; n < 4; ++n)
      bfv[n] = *(const u16x8*)(lB + (wc * 64 + n * 16 + r) * 32 + g * 8);
#pragma unroll
    for (int m = 0; m < 4; ++m)
#pragma unroll
      for (int n = 0; n < 4; ++n) acc[m][n] = mfma16(af[m], bfv[n], acc[m][n]);
  }

#pragma unroll
  for (int m = 0; m < 4; ++m) {
#pragma unroll
    for (int n = 0; n < 4; ++n) {
      int ng = nbase + wc * 64 + n * 16 + r;
      int m0 = mbase + wr * 64 + m * 16 + g * 4;
      if (MODE == 0) {
        int sec = ng >> 10, rem = ng & 1023, hh = rem >> 6, d = rem & 63;
        int b = m0 >> 11, t0 = m0 & 2047;
        size_t bh = (size_t)(b * 16 + hh);
        if (sec == 2) {
          u16x4 o;
#pragma unroll
          for (int e = 0; e < 4; ++e) o[e] = f2bf(acc[m][n][e]);
          *(u16x4*)(vTo + (bh * 64 + d) * 2048 + t0) = o;  // V^T: [bh][d][t]
        } else {
          unsigned short* dst = (sec == 0 ? qo : ko);
#pragma unroll
          for (int e = 0; e < 4; ++e)
            dst[(bh * 2048 + t0 + e) * 64 + d] = f2bf(acc[m][n][e]);
        }
      } else {
#pragma unroll
        for (int e = 0; e < 4; ++e)
          fo[(size_t)(m0 + e) * 1024 + ng] = acc[m][n][e];
      }
    }
  }
}

// ---------------- causal flash attention, head_dim 64, folded E8 bias ----------------
// BARRIER-FREE: 2048 single-wave blocks, each owns 32 q-rows (2 fragments).
// K/V reg-staged from global (K double-buffered, V issue-early single-buffer).
// LDS only for the per-wave P bounce. Defer-max skips most rescales.
__global__ __launch_bounds__(64, 2) void k_attn(const unsigned short* __restrict__ qb,
                                                const unsigned short* __restrict__ kb,
                                                const unsigned short* __restrict__ vTb,
                                                const float* __restrict__ hsc,
                                                const float* __restrict__ hdir,
                                                unsigned short* __restrict__ o2) {
  __shared__ unsigned short lP[32 * 64];  // 4KB per-wave P bounce, XOR-swizzled rows

  const int lane = threadIdx.x;
  const int r = lane & 15, g = lane >> 4;
  // Block decode: bh in low 5 bits (L2 spread); q-tile index permuted so the 8
  // blocks co-resident on one CU (bid = c + 256k) pair long and short diagonals
  // -> per-CU total work 132 +- 2 iters (balanced).
  const int bid = blockIdx.x;
  const int bh = bid & 31;
  const int idx = bid >> 5;               // 0..63
  const int c5 = idx & 7, k8 = idx >> 3;
  const int base8 = (k8 >> 1) * 8 + c5;
  const int a = (k8 & 1) ? (63 - base8) : base8;  // q-tile of 32 rows, 0..63
  const int nk = (a >> 1) + 1;            // 64-wide k-tiles needed (1..32)
  const int qbase = a * 32;
  const int h = bh & 15, bi = bh >> 4;

  const size_t kbase = (size_t)bh * (2048 * 64);
  const size_t vbase = (size_t)bh * (64 * 2048);

  const float LOG2E = 1.44269504088896f;
  const float hs = hsc[h];
  float dir8[8];
#pragma unroll
  for (int j = 0; j < 8; ++j) dir8[j] = hdir[h * 8 + j];

  // Folded Q~ fragments (B-operand of swapped QK^T): lane holds Q~[q=row][d-chunk g].
  u16x8 qc0[2], qc1[2];
  auto QF = [&](int rowbase, u16x8* qc) {
    const unsigned short* qrow = qb + ((size_t)bh * 2048 + rowbase + r) * 64;
    float proj = 0.f;
    u16x8 qv = *(const u16x8*)qrow;
#pragma unroll
    for (int j = 0; j < 8; ++j) proj += bf2f(qv[j]) * dir8[j];
#pragma unroll
    for (int s = 0; s < 2; ++s) {
      u16x8 raw = *(const u16x8*)(qrow + s * 32 + g * 8);
      u16x8 ov;
#pragma unroll
      for (int j = 0; j < 8; ++j) {
        float v = bf2f(raw[j]) * (0.125f * LOG2E);
        if (s == 0 && g == 0) v += (hs * LOG2E) * proj * dir8[j];
        ov[j] = f2bf(v);
      }
      qc[s] = ov;
    }
  };
  QF(qbase, qc0);
  QF(qbase + 16, qc1);

  // Reg staging. K-frag (A-operand): lane holds K[kt*64+ct*16+r][s*32+g*8..+8].
  // V-frag (A-operand of PV): lane holds V^T[dt*16+r][kt*64+s*32+g*8..+8].
  u16x8 kA[8], kB[8], vv[8];
  auto LOADK = [&](u16x8* buf, int kt) {
#pragma unroll
    for (int ct = 0; ct < 4; ++ct)
#pragma unroll
      for (int s = 0; s < 2; ++s)
        buf[ct * 2 + s] =
            *(const u16x8*)(kb + kbase + (size_t)(kt * 64 + ct * 16 + r) * 64 + s * 32 + g * 8);
  };
  auto LOADV = [&](int kt) {
#pragma unroll
    for (int dt = 0; dt < 4; ++dt)
#pragma unroll
      for (int s = 0; s < 2; ++s)
        vv[dt * 2 + s] =
            *(const u16x8*)(vTb + vbase + (size_t)(dt * 16 + r) * 2048 + kt * 64 + s * 32 + g * 8);
  };

  f32x4 accO0[4] = {}, accO1[4] = {};
  float m0 = -1e30f, l0 = 0.f, m1 = -1e30f, l1 = 0.f;
  const int swz = (r & 7) << 4;

  auto COMPUTE = [&](const u16x8* K, int kt) {
    // S = QK^T (swapped: mfma(K, Q)) in log2 domain; lane: S[q=frag row r][k=ct*16+g*4+e]
    f32x4 s0[4], s1[4];
    __builtin_amdgcn_s_setprio(1);
#pragma unroll
    for (int ct = 0; ct < 4; ++ct) {
      f32x4 a0 = {0.f, 0.f, 0.f, 0.f}, a1 = {0.f, 0.f, 0.f, 0.f};
#pragma unroll
      for (int s = 0; s < 2; ++s) {
        a0 = mfma16(K[ct * 2 + s], qc0[s], a0);
        a1 = mfma16(K[ct * 2 + s], qc1[s], a1);
      }
      s0[ct] = a0;
      s1[ct] = a1;
    }
    __builtin_amdgcn_s_setprio(0);

    if (kt == nk - 1) {  // only the last tile crosses the causal diagonal
#pragma unroll
      for (int ct = 0; ct < 4; ++ct)
#pragma unroll
        for (int e = 0; e < 4; ++e) {
          int kk = kt * 64 + ct * 16 + g * 4 + e;
          if (kk > qbase + r) s0[ct][e] = -1e30f;
          if (kk > qbase + 16 + r) s1[ct][e] = -1e30f;
        }
    }

    // per-lane row max (in-register tree + 2 shfl over the 4-lane row group)
    float pm0, pm1;
    {
      float v0 = -1e30f, v1 = -1e30f;
#pragma unroll
      for (int ct = 0; ct < 4; ++ct) {
        v0 = fmaxf(v0, fmaxf(fmaxf(s0[ct][0], s0[ct][1]), fmaxf(s0[ct][2], s0[ct][3])));
        v1 = fmaxf(v1, fmaxf(fmaxf(s1[ct][0], s1[ct][1]), fmaxf(s1[ct][2], s1[ct][3])));
      }
      v0 = fmaxf(v0, __shfl_xor(v0, 16, 64));
      v0 = fmaxf(v0, __shfl_xor(v0, 32, 64));
      v1 = fmaxf(v1, __shfl_xor(v1, 16, 64));
      v1 = fmaxf(v1, __shfl_xor(v1, 32, 64));
      pm0 = v0;
      pm1 = v1;
    }

    // defer-max (T13): skip rescale while max growth <= 8 (log2 domain, P <= 256)
    float mn0 = fmaxf(m0, pm0), mn1 = fmaxf(m1, pm1);
    bool defer = (pm0 - m0 <= 8.f) && (pm1 - m1 <= 8.f);
    if (__all(defer)) {
      mn0 = m0;
      mn1 = m1;
    } else {
      float al0 = exp2f(m0 - mn0), al1 = exp2f(m1 - mn1);
#pragma unroll
      for (int dt = 0; dt < 4; ++dt) {
#pragma unroll
        for (int e = 0; e < 4; ++e) {
          accO0[dt][e] *= al0;
          accO1[dt][e] *= al1;
        }
      }
      l0 *= al0;
      l1 *= al1;
      m0 = mn0;
      m1 = mn1;
    }

    float p0[4][4], p1[4][4];
#pragma unroll
    for (int ct = 0; ct < 4; ++ct)
#pragma unroll
      for (int e = 0; e < 4; ++e) {
        p0[ct][e] = exp2f(s0[ct][e] - mn0);
        p1[ct][e] = exp2f(s1[ct][e] - mn1);
      }
    float rs0 = 0.f, rs1 = 0.f;
#pragma unroll
    for (int ct = 0; ct < 4; ++ct) {
      rs0 += (p0[ct][0] + p0[ct][1]) + (p0[ct][2] + p0[ct][3]);
      rs1 += (p1[ct][0] + p1[ct][1]) + (p1[ct][2] + p1[ct][3]);
    }
    rs0 += __shfl_xor(rs0, 16, 64);
    rs0 += __shfl_xor(rs0, 32, 64);
    rs1 += __shfl_xor(rs1, 16, 64);
    rs1 += __shfl_xor(rs1, 32, 64);
    l0 += rs0;
    l1 += rs1;

    // P bounce: C-layout -> B-operand layout via per-wave LDS (XOR-swizzled rows)
#pragma unroll
    for (int ct = 0; ct < 4; ++ct) {
      u32x2 w0, w1;
      w0[0] = cvtpk(p0[ct][0], p0[ct][1]);
      w0[1] = cvtpk(p0[ct][2], p0[ct][3]);
      w1[0] = cvtpk(p1[ct][0], p1[ct][1]);
      w1[1] = cvtpk(p1[ct][2], p1[ct][3]);
      *(u32x2*)((char*)lP + r * 128 + ((ct * 32 + g * 8) ^ swz)) = w0;
      *(u32x2*)((char*)lP + (16 + r) * 128 + ((ct * 32 + g * 8) ^ swz)) = w1;
    }
    asm volatile("s_waitcnt lgkmcnt(0)" ::: "memory");
    __builtin_amdgcn_sched_barrier(0);

    // O += P @ V (swapped: mfma(V, P)); V frags shared by both q-fragments
    __builtin_amdgcn_s_setprio(1);
#pragma unroll
    for (int s = 0; s < 2; ++s) {
      u16x8 pa0 = *(const u16x8*)((const char*)lP + r * 128 + ((s * 64 + g * 16) ^ swz));
      u16x8 pa1 = *(const u16x8*)((const char*)lP + (16 + r) * 128 + ((s * 64 + g * 16) ^ swz));
#pragma unroll
      for (int dt = 0; dt < 4; ++dt) {
        accO0[dt] = mfma16(vv[dt * 2 + s], pa0, accO0[dt]);
        accO1[dt] = mfma16(vv[dt * 2 + s], pa1, accO1[dt]);
      }
    }
    __builtin_amdgcn_s_setprio(0);
    asm volatile("s_waitcnt lgkmcnt(0)" ::: "memory");
    __builtin_amdgcn_sched_barrier(0);
  };

  LOADK(kA, 0);
  if (nk > 1) LOADK(kB, 1);
  int kt = 0;
  while (true) {
    LOADV(kt);
    COMPUTE(kA, kt);
    ++kt;
    if (kt == nk) break;
    if (kt + 1 < nk) LOADK(kA, kt + 1);
    LOADV(kt);
    COMPUTE(kB, kt);
    ++kt;
    if (kt == nk) break;
    if (kt + 1 < nk) LOADK(kB, kt + 1);
  }

  // epilogue: O/l -> bf16 [B,T,C]
  float inv0 = 1.f / l0, inv1 = 1.f / l1;
#pragma unroll
  for (int dt = 0; dt < 4; ++dt) {
    u16x4 o0, o1;
#pragma unroll
    for (int e = 0; e < 4; ++e) {
      o0[e] = f2bf(accO0[dt][e] * inv0);
      o1[e] = f2bf(accO1[dt][e] * inv1);
    }
    *(u16x4*)(o2 + ((size_t)(bi * 2048 + qbase + r)) * 1024 + h * 64 + dt * 16 + g * 4) = o0;
    *(u16x4*)(o2 + ((size_t)(bi * 2048 + qbase + 16 + r)) * 1024 + h * 64 + dt * 16 + g * 4) = o1;
  }
}

extern "C" void kernel_launch(void* const* d_in, const int* in_sizes, int n_in,
                              void* d_out, int out_size, void* d_ws, size_t ws_size,
                              hipStream_t stream) {
  const float* x    = (const float*)d_in[0];
  const float* wqkv = (const float*)d_in[1];
  const float* wout = (const float*)d_in[2];
  const float* hsc  = (const float*)d_in[3];
  const float* hdir = (const float*)d_in[4];
  float* outp = (float*)d_out;

  char* ws = (char*)d_ws;
  unsigned short* xb    = (unsigned short*)(ws + 0);         //  8 MB  [4096][1024]
  unsigned short* wqkvT = (unsigned short*)(ws + 8388608);   //  6 MB  [3072][1024]
  unsigned short* woutT = (unsigned short*)(ws + 14680064);  //  2 MB  [1024][1024]
  unsigned short* qb    = (unsigned short*)(ws + 16777216);  //  8 MB  [32][2048][64]
  unsigned short* kb    = (unsigned short*)(ws + 25165824);  //  8 MB  [32][2048][64]
  unsigned short* vT    = (unsigned short*)(ws + 33554432);  //  8 MB  [32][64][2048]
  unsigned short* x2b   = (unsigned short*)(ws + 41943040);  //  8 MB  [4096][1024]
  if (ws_size < 50331648u) return;

  k_cast<<<4096, 256, 0, stream>>>(x, xb, 1048576);
  k_transpose<<<dim3(48, 16), 256, 0, stream>>>(wqkv, wqkvT, 1024, 3072);
  k_transpose<<<dim3(16, 16), 256, 0, stream>>>(wout, woutT, 1024, 1024);
  k_gemm<0><<<dim3(24, 32), 256, 0, stream>>>(xb, wqkvT, qb, kb, vT, nullptr);
  k_attn<<<dim3(2048), 64, 0, stream>>>(qb, kb, vT, hsc, hdir, x2b);
  k_gemm<1><<<dim3(8, 32), 256, 0, stream>>>(x2b, woutT, nullptr, nullptr, nullptr, outp);
}

// Round 5
// 119.367 us; speedup vs baseline: 1.2031x; 1.2031x over previous
//
#include <hip/hip_runtime.h>
#include <stdint.h>

// Problem: B=2, T=2048, C=1024, H=16, HD=64. M = B*T = 4096, 3C = 3072.
// Geo bias folded into Q:  q~[d] = q[d]*SCALE + hs*(q[:8]·dir)*dir[d] (d<8)
// log2(e) additionally folded into Q~ so softmax uses exp2 directly.

typedef float f32x4 __attribute__((ext_vector_type(4)));
typedef unsigned short u16x8 __attribute__((ext_vector_type(8)));
typedef unsigned short u16x4 __attribute__((ext_vector_type(4)));
typedef unsigned int u32x2 __attribute__((ext_vector_type(2)));
typedef __bf16 bf16x8 __attribute__((ext_vector_type(8)));

static __device__ __forceinline__ unsigned short f2bf(float f) {
  unsigned u = __float_as_uint(f);
  u += 0x7FFFu + ((u >> 16) & 1u);
  return (unsigned short)(u >> 16);
}
static __device__ __forceinline__ float bf2f(unsigned short s) {
  return __uint_as_float(((unsigned)s) << 16);
}
static __device__ __forceinline__ f32x4 mfma16(u16x8 a, u16x8 b, f32x4 c) {
  return __builtin_amdgcn_mfma_f32_16x16x32_bf16(
      __builtin_bit_cast(bf16x8, a), __builtin_bit_cast(bf16x8, b), c, 0, 0, 0);
}
static __device__ __forceinline__ unsigned cvtpk(float lo, float hi) {
  unsigned d;
  asm("v_cvt_pk_bf16_f32 %0, %1, %2" : "=v"(d) : "v"(lo), "v"(hi));
  return d;
}

#define GLD16(gp, lp) __builtin_amdgcn_global_load_lds( \
    (const __attribute__((address_space(1))) unsigned int*)(gp), \
    (__attribute__((address_space(3))) unsigned int*)(lp), 16, 0, 0)

// ---------------- cast x (fp32 -> bf16) ----------------
__global__ __launch_bounds__(256) void k_cast(const float* __restrict__ in,
                                              unsigned short* __restrict__ out, int n4) {
  int i = blockIdx.x * 256 + threadIdx.x;
  if (i >= n4) return;
  f32x4 v = *(const f32x4*)(in + (size_t)i * 4);
  u16x4 o;
#pragma unroll
  for (int j = 0; j < 4; ++j) o[j] = f2bf(v[j]);
  *(u16x4*)(out + (size_t)i * 4) = o;
}

// ---------------- transpose + cast: out[c][r] = bf16(in[r][c]) ----------------
__global__ __launch_bounds__(256) void k_transpose(const float* __restrict__ in,
                                                   unsigned short* __restrict__ out,
                                                   int R, int Cc) {
  __shared__ float t[64][65];
  int tr = blockIdx.y * 64, tc = blockIdx.x * 64;
  int tx = threadIdx.x & 15, ty = threadIdx.x >> 4;
#pragma unroll
  for (int i = 0; i < 4; ++i) {
    int rr = ty + i * 16;
    f32x4 v = *(const f32x4*)(in + (size_t)(tr + rr) * Cc + tc + tx * 4);
#pragma unroll
    for (int j = 0; j < 4; ++j) t[rr][tx * 4 + j] = v[j];
  }
  __syncthreads();
#pragma unroll
  for (int i = 0; i < 4; ++i) {
    int cc = ty + i * 16;
    int rr = tx * 4;
    u16x4 o;
#pragma unroll
    for (int j = 0; j < 4; ++j) o[j] = f2bf(t[rr + j][cc]);
    *(u16x4*)(out + (size_t)(tc + cc) * R + tr + rr) = o;
  }
}

// ---------------- GEMM: C[m][n] = sum_k A[m][k] * Bt[n][k]  (K=1024, 128x128 tile, BK=32)
template <int MODE>
__global__ __launch_bounds__(256) void k_gemm(const unsigned short* __restrict__ A,
                                              const unsigned short* __restrict__ Bt,
                                              unsigned short* __restrict__ qo,
                                              unsigned short* __restrict__ ko,
                                              unsigned short* __restrict__ vTo,
                                              float* __restrict__ fo) {
  __shared__ unsigned short lA[128 * 32];
  __shared__ unsigned short lB[128 * 32];
  const int tid = threadIdx.x;
  const int lane = tid & 63, wid = tid >> 6;
  const int wr = wid >> 1, wc = wid & 1;
  const int r = lane & 15, g = lane >> 4;
  const int mbase = blockIdx.y * 128;
  const int nbase = blockIdx.x * 128;

  f32x4 acc[4][4] = {};

  for (int kt = 0; kt < 32; ++kt) {
    __syncthreads();
#pragma unroll
    for (int p = 0; p < 2; ++p) {
      int L = p * 4096 + tid * 16;  // byte offset in 8KB tile
      int row = L >> 6;             // 64B per row (32 bf16)
      int blk = (L >> 4) & 3;       // 16B block within row
      GLD16(A + (size_t)(mbase + row) * 1024 + kt * 32 + blk * 8, lA + (L >> 1));
      GLD16(Bt + (size_t)(nbase + row) * 1024 + kt * 32 + blk * 8, lB + (L >> 1));
    }
    __syncthreads();
    u16x8 af[4], bfv[4];
#pragma unroll
    for (int m = 0; m < 4; ++m)
      af[m] = *(const u16x8*)(lA + (wr * 64 + m * 16 + r) * 32 + g * 8);
#pragma unroll
    for (int n = 0; n < 4; ++n)
      bfv[n] = *(const u16x8*)(lB + (wc * 64 + n * 16 + r) * 32 + g * 8);
#pragma unroll
    for (int m = 0; m < 4; ++m)
#pragma unroll
      for (int n = 0; n < 4; ++n) acc[m][n] = mfma16(af[m], bfv[n], acc[m][n]);
  }

#pragma unroll
  for (int m = 0; m < 4; ++m) {
#pragma unroll
    for (int n = 0; n < 4; ++n) {
      int ng = nbase + wc * 64 + n * 16 + r;
      int m0 = mbase + wr * 64 + m * 16 + g * 4;
      if (MODE == 0) {
        int sec = ng >> 10, rem = ng & 1023, hh = rem >> 6, d = rem & 63;
        int b = m0 >> 11, t0 = m0 & 2047;
        size_t bh = (size_t)(b * 16 + hh);
        if (sec == 2) {
          u16x4 o;
#pragma unroll
          for (int e = 0; e < 4; ++e) o[e] = f2bf(acc[m][n][e]);
          *(u16x4*)(vTo + (bh * 64 + d) * 2048 + t0) = o;  // V^T: [bh][d][t]
        } else {
          unsigned short* dst = (sec == 0 ? qo : ko);
#pragma unroll
          for (int e = 0; e < 4; ++e)
            dst[(bh * 2048 + t0 + e) * 64 + d] = f2bf(acc[m][n][e]);
        }
      } else {
#pragma unroll
        for (int e = 0; e < 4; ++e)
          fo[(size_t)(m0 + e) * 1024 + ng] = acc[m][n][e];
      }
    }
  }
}

// ---------------- causal flash attention, head_dim 64, folded E8 bias ----------------
// 1024 blocks x 4 waves, 64 q-rows each (16/wave). LDS 40KB -> 4 blocks/CU
// (16 waves/CU) so independent blocks cover barrier stalls. Block decode puts
// a-values {j, 31-j, 8+j, 23-j} on each CU -> per-CU work sum == 66 exactly.
// Steady-state softmax has ZERO cross-lane ops: lane-partial max triggers the
// (rare) full rescale via __any; l stays lane-partial until the epilogue.
__global__ __launch_bounds__(256) void k_attn(const unsigned short* __restrict__ qb,
                                              const unsigned short* __restrict__ kb,
                                              const unsigned short* __restrict__ vTb,
                                              const float* __restrict__ hsc,
                                              const float* __restrict__ hdir,
                                              unsigned short* __restrict__ o2) {
  __shared__ unsigned short lK[2][64 * 64];   // [buf][kpos][d], XOR-swizzled rows
  __shared__ unsigned short lV[2][64 * 64];   // [buf][d][kpos], XOR-swizzled rows
  __shared__ unsigned short lP[4][16 * 64];   // per-wave P bounce, swizzled

  const int tid = threadIdx.x, lane = tid & 63, wid = tid >> 6;
  const int r = lane & 15, g = lane >> 4;
  // Decode: resident set on a CU is {bid, bid+256, bid+512, bid+768} (round-robin
  // heuristic); give those a = {j, 31-j, 8+j, 23-j} -> sum(nk) = 66 for every CU.
  const int bid = blockIdx.x;
  const int u = bid & 255, kq = bid >> 8;
  const int bh = u & 31, j = u >> 5;  // j in 0..7
  const int a = (kq == 0) ? j : (kq == 1) ? (31 - j) : (kq == 2) ? (8 + j) : (23 - j);
  const int nk = a + 1;
  const int qbase = a * 64;
  const int h = bh & 15, bi = bh >> 4;

  const size_t kbase = (size_t)bh * (2048 * 64);
  const size_t vbase = (size_t)bh * (64 * 2048);

  auto STAGE = [&](int buf, int kt) {
    unsigned short* dK = (unsigned short*)lK[buf];
    unsigned short* dV = (unsigned short*)lV[buf];
#pragma unroll
    for (int p = 0; p < 2; ++p) {
      int L = p * 4096 + tid * 16;
      int row = L >> 7;           // 128B rows (64 bf16)
      int cb = (L >> 4) & 7;
      int cbg = cb ^ (row & 7);   // pre-swizzled source -> swizzled reads, linear dest
      GLD16(kb + kbase + (size_t)(kt * 64 + row) * 64 + cbg * 8, dK + (L >> 1));
      GLD16(vTb + vbase + (size_t)row * 2048 + kt * 64 + cbg * 8, dV + (L >> 1));
    }
  };

  STAGE(0, 0);  // prologue staging overlaps Q-fragment build

  const float LOG2E = 1.44269504088896f;
  const float hs = hsc[h];
  float dir8[8];
#pragma unroll
  for (int j2 = 0; j2 < 8; ++j2) dir8[j2] = hdir[h * 8 + j2];

  // Folded Q~ fragment (B-operand of swapped QK^T): lane holds Q~[q=r][d-chunk g].
  u16x8 qc0, qc1;
  {
    const unsigned short* qrow = qb + ((size_t)bh * 2048 + qbase + wid * 16 + r) * 64;
    float proj = 0.f;
    u16x8 qv = *(const u16x8*)qrow;
#pragma unroll
    for (int j2 = 0; j2 < 8; ++j2) proj += bf2f(qv[j2]) * dir8[j2];
#pragma unroll
    for (int s = 0; s < 2; ++s) {
      u16x8 raw = *(const u16x8*)(qrow + s * 32 + g * 8);
      u16x8 ov;
#pragma unroll
      for (int j2 = 0; j2 < 8; ++j2) {
        float v = bf2f(raw[j2]) * (0.125f * LOG2E);
        if (s == 0 && g == 0) v += (hs * LOG2E) * proj * dir8[j2];
        ov[j2] = f2bf(v);
      }
      if (s == 0) qc0 = ov; else qc1 = ov;
    }
  }

  f32x4 accO[4] = {};
  float mrow = -1e30f, lp = 0.f;   // lp is a LANE-PARTIAL sum (reduced in epilogue)
  unsigned short* pw = &lP[wid][0];
  const int swz = (r & 7) << 4;
  const int qq = qbase + wid * 16 + r;

  for (int kt = 0; kt < nk; ++kt) {
    // top rendezvous: all waves' LDS reads of buf[(kt-1)&1] retired -> restage OK
    asm volatile("s_waitcnt lgkmcnt(0)" ::: "memory");
    __builtin_amdgcn_sched_barrier(0);
    __builtin_amdgcn_s_barrier();
    __builtin_amdgcn_sched_barrier(0);

    if (kt + 1 < nk) STAGE((kt + 1) & 1, kt + 1);

    // counted wait: stage(kt) landed; stage(kt+1)'s 4 loads may stay in flight
    if (kt + 1 < nk) {
      asm volatile("s_waitcnt vmcnt(4)" ::: "memory");
    } else {
      asm volatile("s_waitcnt vmcnt(0)" ::: "memory");
    }
    __builtin_amdgcn_sched_barrier(0);
    __builtin_amdgcn_s_barrier();   // buf[kt&1] staged for ALL waves
    __builtin_amdgcn_sched_barrier(0);

    const char* lKc = (const char*)lK[kt & 1];
    const char* lVc = (const char*)lV[kt & 1];

    // S = (K @ Q~^T)^T in log2 domain: lane holds S[q=r][k=ct*16+g*4+e]
    f32x4 accS[4];
    __builtin_amdgcn_s_setprio(1);
#pragma unroll
    for (int ct = 0; ct < 4; ++ct) {
      f32x4 s4 = {0.f, 0.f, 0.f, 0.f};
      int krow = ct * 16 + r;
      int sw = (krow & 7) << 4;
      u16x8 kf0 = *(const u16x8*)(lKc + krow * 128 + ((g * 16) ^ sw));
      u16x8 kf1 = *(const u16x8*)(lKc + krow * 128 + ((64 + g * 16) ^ sw));
      s4 = mfma16(kf0, qc0, s4);
      s4 = mfma16(kf1, qc1, s4);
      accS[ct] = s4;
    }
    __builtin_amdgcn_s_setprio(0);

    if (kt == nk - 1) {  // only the last tile crosses the causal diagonal
#pragma unroll
      for (int ct = 0; ct < 4; ++ct)
#pragma unroll
        for (int e = 0; e < 4; ++e) {
          int kk = kt * 64 + ct * 16 + g * 4 + e;
          if (kk > qq) accS[ct][e] = -1e30f;
        }
    }

    // lane-partial max; rescale only when some lane's partial breaks the bound.
    float pm;
    {
      float t0 = fmaxf(fmaxf(accS[0][0], accS[0][1]), fmaxf(accS[0][2], accS[0][3]));
      float t1 = fmaxf(fmaxf(accS[1][0], accS[1][1]), fmaxf(accS[1][2], accS[1][3]));
      float t2 = fmaxf(fmaxf(accS[2][0], accS[2][1]), fmaxf(accS[2][2], accS[2][3]));
      float t3 = fmaxf(fmaxf(accS[3][0], accS[3][1]), fmaxf(accS[3][2], accS[3][3]));
      pm = fmaxf(fmaxf(t0, t1), fmaxf(t2, t3));
    }
    if (__any(pm > mrow + 8.f)) {   // rare: true row max needed
      float v = pm;
      v = fmaxf(v, __shfl_xor(v, 16, 64));
      v = fmaxf(v, __shfl_xor(v, 32, 64));   // v = row max (uniform in row group)
      float mn = fmaxf(mrow, v);
      float al = exp2f(mrow - mn);
#pragma unroll
      for (int dt = 0; dt < 4; ++dt)
#pragma unroll
        for (int e = 0; e < 4; ++e) accO[dt][e] *= al;
      lp *= al;
      mrow = mn;
    }

    // P = exp2(S - m); lane-partial l accumulation (no shuffles)
    float p[4][4];
#pragma unroll
    for (int ct = 0; ct < 4; ++ct)
#pragma unroll
      for (int e = 0; e < 4; ++e) p[ct][e] = exp2f(accS[ct][e] - mrow);
#pragma unroll
    for (int ct = 0; ct < 4; ++ct)
      lp += (p[ct][0] + p[ct][1]) + (p[ct][2] + p[ct][3]);

    // P -> bf16 (cvt_pk) -> per-wave LDS bounce (b64 writes, XOR-swizzled)
#pragma unroll
    for (int ct = 0; ct < 4; ++ct) {
      u32x2 w;
      w[0] = cvtpk(p[ct][0], p[ct][1]);
      w[1] = cvtpk(p[ct][2], p[ct][3]);
      *(u32x2*)((char*)pw + r * 128 + ((ct * 32 + g * 8) ^ swz)) = w;
    }
    asm volatile("s_waitcnt lgkmcnt(0)" ::: "memory");
    __builtin_amdgcn_sched_barrier(0);

    // O^T += V^T @ P^T (swapped): lane gets O[q=r][d=dt*16+g*4+e]
    __builtin_amdgcn_s_setprio(1);
#pragma unroll
    for (int s = 0; s < 2; ++s) {
      u16x8 pa = *(const u16x8*)((const char*)pw + r * 128 + ((s * 64 + g * 16) ^ swz));
#pragma unroll
      for (int dt = 0; dt < 4; ++dt) {
        int dd = dt * 16 + r;
        u16x8 vf = *(const u16x8*)(lVc + dd * 128 + ((s * 64 + g * 16) ^ ((dd & 7) << 4)));
        accO[dt] = mfma16(vf, pa, accO[dt]);
      }
    }
    __builtin_amdgcn_s_setprio(0);
  }

  // epilogue: reduce lane-partial l once, then O/l -> bf16 [B,T,C]
  lp += __shfl_xor(lp, 16, 64);
  lp += __shfl_xor(lp, 32, 64);
  float inv = 1.f / lp;
#pragma unroll
  for (int dt = 0; dt < 4; ++dt) {
    u16x4 o;
#pragma unroll
    for (int e = 0; e < 4; ++e) o[e] = f2bf(accO[dt][e] * inv);
    *(u16x4*)(o2 + ((size_t)(bi * 2048 + qq)) * 1024 + h * 64 + dt * 16 + g * 4) = o;
  }
}

extern "C" void kernel_launch(void* const* d_in, const int* in_sizes, int n_in,
                              void* d_out, int out_size, void* d_ws, size_t ws_size,
                              hipStream_t stream) {
  const float* x    = (const float*)d_in[0];
  const float* wqkv = (const float*)d_in[1];
  const float* wout = (const float*)d_in[2];
  const float* hsc  = (const float*)d_in[3];
  const float* hdir = (const float*)d_in[4];
  float* outp = (float*)d_out;

  char* ws = (char*)d_ws;
  unsigned short* xb    = (unsigned short*)(ws + 0);         //  8 MB  [4096][1024]
  unsigned short* wqkvT = (unsigned short*)(ws + 8388608);   //  6 MB  [3072][1024]
  unsigned short* woutT = (unsigned short*)(ws + 14680064);  //  2 MB  [1024][1024]
  unsigned short* qb    = (unsigned short*)(ws + 16777216);  //  8 MB  [32][2048][64]
  unsigned short* kb    = (unsigned short*)(ws + 25165824);  //  8 MB  [32][2048][64]
  unsigned short* vT    = (unsigned short*)(ws + 33554432);  //  8 MB  [32][64][2048]
  unsigned short* x2b   = (unsigned short*)(ws + 41943040);  //  8 MB  [4096][1024]
  if (ws_size < 50331648u) return;

  k_cast<<<4096, 256, 0, stream>>>(x, xb, 1048576);
  k_transpose<<<dim3(48, 16), 256, 0, stream>>>(wqkv, wqkvT, 1024, 3072);
  k_transpose<<<dim3(16, 16), 256, 0, stream>>>(wout, woutT, 1024, 1024);
  k_gemm<0><<<dim3(24, 32), 256, 0, stream>>>(xb, wqkvT, qb, kb, vT, nullptr);
  k_attn<<<dim3(1024), 256, 0, stream>>>(qb, kb, vT, hsc, hdir, x2b);
  k_gemm<1><<<dim3(8, 32), 256, 0, stream>>>(x2b, woutT, nullptr, nullptr, nullptr, outp);
}